// Round 1
// baseline (1277.696 us; speedup 1.0000x reference)
//
#include <hip/hip_runtime.h>
#include <math.h>

#define IN_F 128
#define HID 64
#define N_NODES 100000
#define N_EDGES 1000000

// ---------------------------------------------------------------------------
// Kernel 1: H = feat @ W_feat + b_feat  (fused: s_out[row] = dot(H[row], a_eff))
//   mode 0: a_eff[j] = W_att[j] + W_att[64+j]/3   (h0 term + its share of enc)
//   mode 1/2: a_eff[j] = W_att[64+j]/3            (enc share only)
// 64 rows x 64 cols tile per block; thread = 4x4 register tile.
// ---------------------------------------------------------------------------
__global__ __launch_bounds__(256)
void lin_att_kernel(const float* __restrict__ feat,
                    const float* __restrict__ W,       // [128][64] row-major
                    const float* __restrict__ b_feat,  // [64]
                    const float* __restrict__ W_att,   // [128]
                    float* __restrict__ H,             // [N][64]
                    float* __restrict__ s_out,         // [N]
                    int mode)
{
    __shared__ float sW[IN_F * HID];     // 32 KB, reused across k-chunks
    __shared__ float sFt[64 * 68];       // transposed feat tile [k][row], pad->68
    __shared__ float sAeff[HID];

    const int t = threadIdx.x;
    for (int i = t; i < IN_F * HID; i += 256) sW[i] = W[i];
    if (t < HID) {
        float a0 = W_att[t], a1 = W_att[HID + t];
        sAeff[t] = (mode == 0) ? (a0 + a1 * (1.0f / 3.0f)) : (a1 * (1.0f / 3.0f));
    }

    const int tx = t & 15;   // col group: cols 4*tx..4*tx+3
    const int ty = t >> 4;   // row group: rows 4*ty..4*ty+3
    const int rowBase = blockIdx.x * 64;

    float acc[4][4];
    {
        float b0 = b_feat[4 * tx + 0], b1 = b_feat[4 * tx + 1];
        float b2 = b_feat[4 * tx + 2], b3 = b_feat[4 * tx + 3];
        #pragma unroll
        for (int r = 0; r < 4; ++r) { acc[r][0] = b0; acc[r][1] = b1; acc[r][2] = b2; acc[r][3] = b3; }
    }

    for (int k0 = 0; k0 < IN_F; k0 += 64) {
        __syncthreads();
        // stage feat[rowBase..rowBase+63][k0..k0+63] transposed into sFt[k][row]
        #pragma unroll
        for (int i = 0; i < 16; ++i) {
            int idx = t + 256 * i;        // 0..4095
            int row = idx >> 6;
            int kk  = idx & 63;
            int gr  = rowBase + row;
            float v = (gr < N_NODES) ? feat[gr * IN_F + k0 + kk] : 0.0f;
            sFt[kk * 68 + row] = v;
        }
        __syncthreads();

        const float* wp = &sW[k0 * HID + 4 * tx];
        const float* fp = &sFt[4 * ty];
        #pragma unroll 8
        for (int kk = 0; kk < 64; ++kk) {
            float4 wv = *(const float4*)(wp + kk * HID);
            float4 fv = *(const float4*)(fp + kk * 68);
            acc[0][0] = fmaf(fv.x, wv.x, acc[0][0]);
            acc[0][1] = fmaf(fv.x, wv.y, acc[0][1]);
            acc[0][2] = fmaf(fv.x, wv.z, acc[0][2]);
            acc[0][3] = fmaf(fv.x, wv.w, acc[0][3]);
            acc[1][0] = fmaf(fv.y, wv.x, acc[1][0]);
            acc[1][1] = fmaf(fv.y, wv.y, acc[1][1]);
            acc[1][2] = fmaf(fv.y, wv.z, acc[1][2]);
            acc[1][3] = fmaf(fv.y, wv.w, acc[1][3]);
            acc[2][0] = fmaf(fv.z, wv.x, acc[2][0]);
            acc[2][1] = fmaf(fv.z, wv.y, acc[2][1]);
            acc[2][2] = fmaf(fv.z, wv.z, acc[2][2]);
            acc[2][3] = fmaf(fv.z, wv.w, acc[2][3]);
            acc[3][0] = fmaf(fv.w, wv.x, acc[3][0]);
            acc[3][1] = fmaf(fv.w, wv.y, acc[3][1]);
            acc[3][2] = fmaf(fv.w, wv.z, acc[3][2]);
            acc[3][3] = fmaf(fv.w, wv.w, acc[3][3]);
        }
    }

    float ae0 = sAeff[4 * tx + 0], ae1 = sAeff[4 * tx + 1];
    float ae2 = sAeff[4 * tx + 2], ae3 = sAeff[4 * tx + 3];

    #pragma unroll
    for (int r = 0; r < 4; ++r) {
        int gr = rowBase + 4 * ty + r;
        if (gr < N_NODES) {
            float4 o = make_float4(acc[r][0], acc[r][1], acc[r][2], acc[r][3]);
            *(float4*)&H[gr * HID + 4 * tx] = o;
            float p = acc[r][0] * ae0 + acc[r][1] * ae1 + acc[r][2] * ae2 + acc[r][3] * ae3;
            // reduce across the 16 tx lanes (lane bits 0..3 within the wave)
            p += __shfl_xor(p, 1, 64);
            p += __shfl_xor(p, 2, 64);
            p += __shfl_xor(p, 4, 64);
            p += __shfl_xor(p, 8, 64);
            if (tx == 0) s_out[gr] = p;
        }
    }
}

// ---------------------------------------------------------------------------
// Kernel 2: per-edge unnormalized softmax weight + segment denominator
// ---------------------------------------------------------------------------
__global__ __launch_bounds__(256)
void edge_score_kernel(const int* __restrict__ e0a, const int* __restrict__ e1a,
                       const int* __restrict__ e2a,
                       const float* __restrict__ p0, const float* __restrict__ q1,
                       const float* __restrict__ q2,
                       const float* __restrict__ b_att,
                       float* __restrict__ ex_out, float* __restrict__ denom)
{
    int i = blockIdx.x * 256 + threadIdx.x;
    if (i < N_EDGES) {
        int e0 = e0a[i];
        float x = p0[e0] + q1[e1a[i]] + q2[e2a[i]] + b_att[0];
        // tanh(x) in [-1,1] => exp never overflows; softmax shift-invariant,
        // so skipping the segment-max is exact.
        float ex = __expf(tanhf(x));
        ex_out[i] = ex;
        atomicAdd(&denom[e0], ex);
    }
}

// ---------------------------------------------------------------------------
// Kernel 3: out[n][j] = bias[j]
// ---------------------------------------------------------------------------
__global__ __launch_bounds__(256)
void init_out_kernel(float* __restrict__ out, const float* __restrict__ bias)
{
    int i = blockIdx.x * 256 + threadIdx.x;
    if (i < N_NODES * HID) out[i] = bias[i & (HID - 1)];
}

// ---------------------------------------------------------------------------
// Kernel 4: out[e0] += (ex/denom[e0]) * (H0[e0]+H1[e1]+H2[e2])/3
// 16 lanes per edge, float4 per lane, 4 scalar atomics per lane.
// ---------------------------------------------------------------------------
__global__ __launch_bounds__(256)
void aggregate_kernel(const int* __restrict__ e0a, const int* __restrict__ e1a,
                      const int* __restrict__ e2a,
                      const float* __restrict__ H0, const float* __restrict__ H1,
                      const float* __restrict__ H2,
                      const float* __restrict__ exv, const float* __restrict__ denom,
                      float* __restrict__ out)
{
    int gid  = blockIdx.x * 256 + threadIdx.x;
    int edge = gid >> 4;
    int sub  = gid & 15;
    if (edge < N_EDGES) {
        int e0 = e0a[edge], e1 = e1a[edge], e2 = e2a[edge];
        float w = exv[edge] / denom[e0] * (1.0f / 3.0f);
        float4 h0 = *(const float4*)&H0[e0 * HID + 4 * sub];
        float4 h1 = *(const float4*)&H1[e1 * HID + 4 * sub];
        float4 h2 = *(const float4*)&H2[e2 * HID + 4 * sub];
        float sx = (h0.x + h1.x + h2.x) * w;
        float sy = (h0.y + h1.y + h2.y) * w;
        float sz = (h0.z + h1.z + h2.z) * w;
        float sw = (h0.w + h1.w + h2.w) * w;
        float* o = &out[e0 * HID + 4 * sub];
        atomicAdd(o + 0, sx);
        atomicAdd(o + 1, sy);
        atomicAdd(o + 2, sz);
        atomicAdd(o + 3, sw);
    }
}

// ---------------------------------------------------------------------------
extern "C" void kernel_launch(void* const* d_in, const int* in_sizes, int n_in,
                              void* d_out, int out_size, void* d_ws, size_t ws_size,
                              hipStream_t stream)
{
    const float* feat0  = (const float*)d_in[0];
    const float* feat1  = (const float*)d_in[1];
    const float* feat2  = (const float*)d_in[2];
    const int*   edge0  = (const int*)d_in[3];
    const int*   edge1  = (const int*)d_in[4];
    const int*   edge2  = (const int*)d_in[5];
    const float* W_feat = (const float*)d_in[6];
    const float* b_feat = (const float*)d_in[7];
    const float* W_att  = (const float*)d_in[8];
    const float* b_att  = (const float*)d_in[9];
    const float* bias   = (const float*)d_in[10];
    float* out = (float*)d_out;

    float* ws    = (float*)d_ws;
    float* H0    = ws;                          // 6.4M floats
    float* H1    = H0 + (size_t)N_NODES * HID;  // 6.4M
    float* H2    = H1 + (size_t)N_NODES * HID;  // 6.4M
    float* p0    = H2 + (size_t)N_NODES * HID;  // 100k
    float* q1    = p0 + N_NODES;                // 100k
    float* q2    = q1 + N_NODES;                // 100k
    float* denom = q2 + N_NODES;                // 100k
    float* exv   = denom + N_NODES;             // 1M
    // total ~20.6M floats = 82.4 MB

    hipMemsetAsync(denom, 0, N_NODES * sizeof(float), stream);

    dim3 blk(256);
    int tiles = (N_NODES + 63) / 64;
    lin_att_kernel<<<tiles, blk, 0, stream>>>(feat0, W_feat, b_feat, W_att, H0, p0, 0);
    lin_att_kernel<<<tiles, blk, 0, stream>>>(feat1, W_feat, b_feat, W_att, H1, q1, 1);
    lin_att_kernel<<<tiles, blk, 0, stream>>>(feat2, W_feat, b_feat, W_att, H2, q2, 2);

    edge_score_kernel<<<(N_EDGES + 255) / 256, blk, 0, stream>>>(
        edge0, edge1, edge2, p0, q1, q2, b_att, exv, denom);

    init_out_kernel<<<(N_NODES * HID + 255) / 256, blk, 0, stream>>>(out, bias);

    aggregate_kernel<<<((size_t)N_EDGES * 16 + 255) / 256, blk, 0, stream>>>(
        edge0, edge1, edge2, H0, H1, H2, exv, denom, out);
}

// Round 2
// 574.180 us; speedup vs baseline: 2.2253x; 2.2253x over previous
//
#include <hip/hip_runtime.h>
#include <math.h>

#define IN_F 128
#define HID 64
#define N_NODES 100000
#define N_EDGES 1000000
#define SCAN_BLOCKS 98   // ceil(N_NODES / 1024)

// ---------------------------------------------------------------------------
// Kernel 1: H = feat @ W_feat + b_feat  (fused: s_out[row] = dot(H[row], a_eff))
//   mode 0: a_eff[j] = W_att[j] + W_att[64+j]/3
//   mode 1/2: a_eff[j] = W_att[64+j]/3
// ---------------------------------------------------------------------------
__global__ __launch_bounds__(256)
void lin_att_kernel(const float* __restrict__ feat,
                    const float* __restrict__ W,
                    const float* __restrict__ b_feat,
                    const float* __restrict__ W_att,
                    float* __restrict__ H,
                    float* __restrict__ s_out,
                    int mode)
{
    __shared__ float sW[IN_F * HID];
    __shared__ float sFt[64 * 68];
    __shared__ float sAeff[HID];

    const int t = threadIdx.x;
    for (int i = t; i < IN_F * HID; i += 256) sW[i] = W[i];
    if (t < HID) {
        float a0 = W_att[t], a1 = W_att[HID + t];
        sAeff[t] = (mode == 0) ? (a0 + a1 * (1.0f / 3.0f)) : (a1 * (1.0f / 3.0f));
    }

    const int tx = t & 15;
    const int ty = t >> 4;
    const int rowBase = blockIdx.x * 64;

    float acc[4][4];
    {
        float b0 = b_feat[4 * tx + 0], b1 = b_feat[4 * tx + 1];
        float b2 = b_feat[4 * tx + 2], b3 = b_feat[4 * tx + 3];
        #pragma unroll
        for (int r = 0; r < 4; ++r) { acc[r][0] = b0; acc[r][1] = b1; acc[r][2] = b2; acc[r][3] = b3; }
    }

    for (int k0 = 0; k0 < IN_F; k0 += 64) {
        __syncthreads();
        #pragma unroll
        for (int i = 0; i < 16; ++i) {
            int idx = t + 256 * i;
            int row = idx >> 6;
            int kk  = idx & 63;
            int gr  = rowBase + row;
            float v = (gr < N_NODES) ? feat[gr * IN_F + k0 + kk] : 0.0f;
            sFt[kk * 68 + row] = v;
        }
        __syncthreads();

        const float* wp = &sW[k0 * HID + 4 * tx];
        const float* fp = &sFt[4 * ty];
        #pragma unroll 8
        for (int kk = 0; kk < 64; ++kk) {
            float4 wv = *(const float4*)(wp + kk * HID);
            float4 fv = *(const float4*)(fp + kk * 68);
            acc[0][0] = fmaf(fv.x, wv.x, acc[0][0]);
            acc[0][1] = fmaf(fv.x, wv.y, acc[0][1]);
            acc[0][2] = fmaf(fv.x, wv.z, acc[0][2]);
            acc[0][3] = fmaf(fv.x, wv.w, acc[0][3]);
            acc[1][0] = fmaf(fv.y, wv.x, acc[1][0]);
            acc[1][1] = fmaf(fv.y, wv.y, acc[1][1]);
            acc[1][2] = fmaf(fv.y, wv.z, acc[1][2]);
            acc[1][3] = fmaf(fv.y, wv.w, acc[1][3]);
            acc[2][0] = fmaf(fv.z, wv.x, acc[2][0]);
            acc[2][1] = fmaf(fv.z, wv.y, acc[2][1]);
            acc[2][2] = fmaf(fv.z, wv.z, acc[2][2]);
            acc[2][3] = fmaf(fv.z, wv.w, acc[2][3]);
            acc[3][0] = fmaf(fv.w, wv.x, acc[3][0]);
            acc[3][1] = fmaf(fv.w, wv.y, acc[3][1]);
            acc[3][2] = fmaf(fv.w, wv.z, acc[3][2]);
            acc[3][3] = fmaf(fv.w, wv.w, acc[3][3]);
        }
    }

    float ae0 = sAeff[4 * tx + 0], ae1 = sAeff[4 * tx + 1];
    float ae2 = sAeff[4 * tx + 2], ae3 = sAeff[4 * tx + 3];

    #pragma unroll
    for (int r = 0; r < 4; ++r) {
        int gr = rowBase + 4 * ty + r;
        if (gr < N_NODES) {
            float4 o = make_float4(acc[r][0], acc[r][1], acc[r][2], acc[r][3]);
            *(float4*)&H[gr * HID + 4 * tx] = o;
            float p = acc[r][0] * ae0 + acc[r][1] * ae1 + acc[r][2] * ae2 + acc[r][3] * ae3;
            p += __shfl_xor(p, 1, 64);
            p += __shfl_xor(p, 2, 64);
            p += __shfl_xor(p, 4, 64);
            p += __shfl_xor(p, 8, 64);
            if (tx == 0) s_out[gr] = p;
        }
    }
}

// ---------------------------------------------------------------------------
// CSR build: histogram -> scan (3 kernels) -> scatter(+score)
// ---------------------------------------------------------------------------
__global__ __launch_bounds__(256)
void hist_kernel(const int* __restrict__ e0a, int* __restrict__ counts)
{
    int i = blockIdx.x * 256 + threadIdx.x;
    if (i < N_EDGES) atomicAdd(&counts[e0a[i]], 1);
}

// blockwise scan: each block covers 1024 counts (256 threads x 4)
__global__ __launch_bounds__(256)
void scan1_kernel(const int* __restrict__ counts, int* __restrict__ offsets,
                  int* __restrict__ blockSums)
{
    __shared__ int s[256];
    int t = threadIdx.x;
    int base = blockIdx.x * 1024 + t * 4;
    int c0 = (base + 0 < N_NODES) ? counts[base + 0] : 0;
    int c1 = (base + 1 < N_NODES) ? counts[base + 1] : 0;
    int c2 = (base + 2 < N_NODES) ? counts[base + 2] : 0;
    int c3 = (base + 3 < N_NODES) ? counts[base + 3] : 0;
    int tsum = c0 + c1 + c2 + c3;
    s[t] = tsum;
    __syncthreads();
    for (int off = 1; off < 256; off <<= 1) {
        int v = (t >= off) ? s[t - off] : 0;
        __syncthreads();
        s[t] += v;
        __syncthreads();
    }
    int excl = s[t] - tsum;
    if (base + 0 < N_NODES) offsets[base + 0] = excl;
    if (base + 1 < N_NODES) offsets[base + 1] = excl + c0;
    if (base + 2 < N_NODES) offsets[base + 2] = excl + c0 + c1;
    if (base + 3 < N_NODES) offsets[base + 3] = excl + c0 + c1 + c2;
    if (t == 255) blockSums[blockIdx.x] = s[255];
}

__global__ void scan2_kernel(int* __restrict__ blockSums)
{
    if (threadIdx.x == 0 && blockIdx.x == 0) {
        int run = 0;
        for (int i = 0; i < SCAN_BLOCKS; ++i) {
            int v = blockSums[i];
            blockSums[i] = run;
            run += v;
        }
    }
}

__global__ __launch_bounds__(256)
void scan3_kernel(int* __restrict__ offsets, int* __restrict__ cursor,
                  const int* __restrict__ blockSums)
{
    int t = threadIdx.x;
    int base = blockIdx.x * 1024 + t * 4;
    int add = blockSums[blockIdx.x];
    #pragma unroll
    for (int k = 0; k < 4; ++k) {
        int i = base + k;
        if (i < N_NODES) {
            int v = offsets[i] + add;
            offsets[i] = v;
            cursor[i] = v;
        }
    }
}

// scatter: compute edge score and place (e1, e2, ex) in dest-sorted order
__global__ __launch_bounds__(256)
void scatter_kernel(const int* __restrict__ e0a, const int* __restrict__ e1a,
                    const int* __restrict__ e2a,
                    const float* __restrict__ p0, const float* __restrict__ q1,
                    const float* __restrict__ q2, const float* __restrict__ b_att,
                    int* __restrict__ cursor,
                    int* __restrict__ e1s, int* __restrict__ e2s,
                    float* __restrict__ exs)
{
    int i = blockIdx.x * 256 + threadIdx.x;
    if (i < N_EDGES) {
        int e0 = e0a[i], e1 = e1a[i], e2 = e2a[i];
        float x = p0[e0] + q1[e1] + q2[e2] + b_att[0];
        // tanh in [-1,1] => exp(tanh) safe; softmax shift-invariance makes
        // skipping the segment-max exact.
        float ex = __expf(tanhf(x));
        int pos = atomicAdd(&cursor[e0], 1);
        e1s[pos] = e1;
        e2s[pos] = e2;
        exs[pos] = ex;
    }
}

// ---------------------------------------------------------------------------
// Aggregate, CSR form: 16 lanes per node, no atomics.
// out[n] = bias + (1/3)*H0[n] + (1/(3*denom)) * sum_e ex_e*(H1[e1]+H2[e2])
// (uses sum_e softmax_w = 1; empty nodes -> bias only)
// ---------------------------------------------------------------------------
__global__ __launch_bounds__(256)
void aggregate_csr_kernel(const int* __restrict__ offsets, const int* __restrict__ counts,
                          const int* __restrict__ e1s, const int* __restrict__ e2s,
                          const float* __restrict__ exs,
                          const float* __restrict__ H0, const float* __restrict__ H1,
                          const float* __restrict__ H2,
                          const float* __restrict__ bias,
                          float* __restrict__ out)
{
    int gid  = blockIdx.x * 256 + threadIdx.x;
    int node = gid >> 4;
    int sub  = gid & 15;
    if (node >= N_NODES) return;

    int start = offsets[node];
    int cnt   = counts[node];

    float denom = 0.0f;
    for (int j = 0; j < cnt; ++j) denom += exs[start + j];   // broadcast loads

    float ax = 0.0f, ay = 0.0f, az = 0.0f, aw = 0.0f;
    for (int j = 0; j < cnt; ++j) {
        float w = exs[start + j];
        int e1 = e1s[start + j];
        int e2 = e2s[start + j];
        float4 h1 = *(const float4*)&H1[e1 * HID + 4 * sub];
        float4 h2 = *(const float4*)&H2[e2 * HID + 4 * sub];
        ax = fmaf(w, h1.x + h2.x, ax);
        ay = fmaf(w, h1.y + h2.y, ay);
        az = fmaf(w, h1.z + h2.z, az);
        aw = fmaf(w, h1.w + h2.w, aw);
    }

    float4 h0 = *(const float4*)&H0[node * HID + 4 * sub];
    float4 bv = *(const float4*)&bias[4 * sub];
    float third = (cnt > 0) ? (1.0f / 3.0f) : 0.0f;
    float inv   = (cnt > 0) ? 1.0f / (3.0f * denom) : 0.0f;

    float4 o;
    o.x = bv.x + third * h0.x + inv * ax;
    o.y = bv.y + third * h0.y + inv * ay;
    o.z = bv.z + third * h0.z + inv * az;
    o.w = bv.w + third * h0.w + inv * aw;
    *(float4*)&out[node * HID + 4 * sub] = o;
}

// ---------------------------------------------------------------------------
extern "C" void kernel_launch(void* const* d_in, const int* in_sizes, int n_in,
                              void* d_out, int out_size, void* d_ws, size_t ws_size,
                              hipStream_t stream)
{
    const float* feat0  = (const float*)d_in[0];
    const float* feat1  = (const float*)d_in[1];
    const float* feat2  = (const float*)d_in[2];
    const int*   edge0  = (const int*)d_in[3];
    const int*   edge1  = (const int*)d_in[4];
    const int*   edge2  = (const int*)d_in[5];
    const float* W_feat = (const float*)d_in[6];
    const float* b_feat = (const float*)d_in[7];
    const float* W_att  = (const float*)d_in[8];
    const float* b_att  = (const float*)d_in[9];
    const float* bias   = (const float*)d_in[10];
    float* out = (float*)d_out;

    float* ws = (float*)d_ws;
    float* H0  = ws;                           // 6.4M floats
    float* H1  = H0 + (size_t)N_NODES * HID;   // 6.4M
    float* H2  = H1 + (size_t)N_NODES * HID;   // 6.4M
    float* p0  = H2 + (size_t)N_NODES * HID;   // 100k
    float* q1  = p0 + N_NODES;                 // 100k
    float* q2  = q1 + N_NODES;                 // 100k
    float* exs = q2 + N_NODES;                 // 1M
    int* counts    = (int*)(exs + N_EDGES);    // 100k
    int* offsets   = counts + N_NODES;         // 100k
    int* cursor    = offsets + N_NODES;        // 100k
    int* e1s       = cursor + N_NODES;         // 1M
    int* e2s       = e1s + N_EDGES;            // 1M
    int* blockSums = e2s + N_EDGES;            // 128
    // total ~22.9M elems * 4B ~= 92 MB

    hipMemsetAsync(counts, 0, N_NODES * sizeof(int), stream);

    dim3 blk(256);
    int tiles = (N_NODES + 63) / 64;
    lin_att_kernel<<<tiles, blk, 0, stream>>>(feat0, W_feat, b_feat, W_att, H0, p0, 0);
    lin_att_kernel<<<tiles, blk, 0, stream>>>(feat1, W_feat, b_feat, W_att, H1, q1, 1);
    lin_att_kernel<<<tiles, blk, 0, stream>>>(feat2, W_feat, b_feat, W_att, H2, q2, 2);

    hist_kernel<<<(N_EDGES + 255) / 256, blk, 0, stream>>>(edge0, counts);
    scan1_kernel<<<SCAN_BLOCKS, blk, 0, stream>>>(counts, offsets, blockSums);
    scan2_kernel<<<1, 64, 0, stream>>>(blockSums);
    scan3_kernel<<<SCAN_BLOCKS, blk, 0, stream>>>(offsets, cursor, blockSums);

    scatter_kernel<<<(N_EDGES + 255) / 256, blk, 0, stream>>>(
        edge0, edge1, edge2, p0, q1, q2, b_att, cursor, e1s, e2s, exs);

    aggregate_csr_kernel<<<((size_t)N_NODES * 16 + 255) / 256, blk, 0, stream>>>(
        offsets, counts, e1s, e2s, exs, H0, H1, H2, bias, out);
}

// Round 3
// 394.447 us; speedup vs baseline: 3.2392x; 1.4557x over previous
//
#include <hip/hip_runtime.h>
#include <math.h>

#define IN_F 128
#define HID 64
#define N_NODES 100000
#define N_EDGES 1000000
#define SCAN_BLOCKS 98   // ceil(N_NODES / 1024)

typedef __attribute__((ext_vector_type(8))) short bf16x8;
typedef __attribute__((ext_vector_type(4))) float f32x4;

// round-to-nearest-even fp32 -> bf16 (inputs finite)
static __device__ __forceinline__ short f2bf(float f) {
    union { float f; unsigned u; } v; v.f = f;
    unsigned r = v.u + 0x7fffu + ((v.u >> 16) & 1u);
    return (short)(r >> 16);
}

// ---------------------------------------------------------------------------
// Fused 3x GEMM via bf16 MFMA: H = feat @ W + b  (+ attention scalar s_out)
// blockIdx.y selects (feat, H, s_out, mode). Block = 256 thr = 4 waves,
// each wave computes a 16-row x 64-col strip with 16x16x32 MFMA.
//   A-frag: lane m=l&15, k=8*quad+j  (from global, 2x float4 -> 8 bf16)
//   B-frag: lane n=l&15, k=8*quad+j  (from LDS sWT[col][k])
//   C/D:    col=l&15, row=4*quad+reg   [per m89/m91 verified mapping]
// ---------------------------------------------------------------------------
__global__ __launch_bounds__(256)
void lin_att_mfma(const float* __restrict__ feat0, const float* __restrict__ feat1,
                  const float* __restrict__ feat2,
                  const float* __restrict__ W, const float* __restrict__ b_feat,
                  const float* __restrict__ W_att,
                  float* __restrict__ H0, float* __restrict__ H1, float* __restrict__ H2,
                  float* __restrict__ p0, float* __restrict__ q1, float* __restrict__ q2)
{
    const int which = blockIdx.y;
    const float* feat = (which == 0) ? feat0 : (which == 1) ? feat1 : feat2;
    float* H    = (which == 0) ? H0 : (which == 1) ? H1 : H2;
    float* sOut = (which == 0) ? p0 : (which == 1) ? q1 : q2;

    __shared__ short sWT[HID * IN_F];   // [col][k] bf16, 16 KB

    const int t = threadIdx.x;
    // stage W transposed as bf16
    for (int i = t; i < (IN_F * HID) / 4; i += 256) {
        int k  = i >> 4;            // 0..127
        int c4 = (i & 15) * 4;      // col base
        float4 w = *(const float4*)&W[k * HID + c4];
        sWT[(c4 + 0) * IN_F + k] = f2bf(w.x);
        sWT[(c4 + 1) * IN_F + k] = f2bf(w.y);
        sWT[(c4 + 2) * IN_F + k] = f2bf(w.z);
        sWT[(c4 + 3) * IN_F + k] = f2bf(w.w);
    }
    __syncthreads();

    const int wv = t >> 6;          // wave 0..3
    const int l  = t & 63;          // lane
    const int n  = l & 15;          // col-in-tile / row-in-tile
    const int q  = l >> 4;          // quad 0..3
    const int rowBase = blockIdx.x * 64 + wv * 16;

    // B-fragments (shared across waves' rows): [c][s]
    bf16x8 Bf[4][4];
    #pragma unroll
    for (int c = 0; c < 4; ++c)
        #pragma unroll
        for (int s = 0; s < 4; ++s)
            Bf[c][s] = *(const bf16x8*)&sWT[(16 * c + n) * IN_F + 32 * s + 8 * q];

    f32x4 acc[4];
    #pragma unroll
    for (int c = 0; c < 4; ++c) {
        float bv = b_feat[16 * c + n];
        acc[c][0] = bv; acc[c][1] = bv; acc[c][2] = bv; acc[c][3] = bv;
    }

    const int gRow = rowBase + n;
    const int lr = (gRow < N_NODES) ? gRow : (N_NODES - 1);   // clamp loads

    #pragma unroll
    for (int s = 0; s < 4; ++s) {
        const float* ap = &feat[(size_t)lr * IN_F + 32 * s + 8 * q];
        float4 x0 = *(const float4*)ap;
        float4 x1 = *(const float4*)(ap + 4);
        bf16x8 a;
        a[0] = f2bf(x0.x); a[1] = f2bf(x0.y); a[2] = f2bf(x0.z); a[3] = f2bf(x0.w);
        a[4] = f2bf(x1.x); a[5] = f2bf(x1.y); a[6] = f2bf(x1.z); a[7] = f2bf(x1.w);
        #pragma unroll
        for (int c = 0; c < 4; ++c)
            acc[c] = __builtin_amdgcn_mfma_f32_16x16x32_bf16(a, Bf[c][s], acc[c], 0, 0, 0);
    }

    // epilogue: store H + fused attention scalar
    float part[4] = {0.f, 0.f, 0.f, 0.f};
    #pragma unroll
    for (int c = 0; c < 4; ++c) {
        int col = 16 * c + n;
        float a0 = W_att[col], a1 = W_att[HID + col];
        float ae = (which == 0) ? (a0 + a1 * (1.0f / 3.0f)) : (a1 * (1.0f / 3.0f));
        #pragma unroll
        for (int r = 0; r < 4; ++r) {
            int row = rowBase + 4 * q + r;
            if (row < N_NODES) H[(size_t)row * HID + col] = acc[c][r];
            part[r] = fmaf(acc[c][r], ae, part[r]);
        }
    }
    #pragma unroll
    for (int r = 0; r < 4; ++r) {
        float p = part[r];
        p += __shfl_xor(p, 1, 64);
        p += __shfl_xor(p, 2, 64);
        p += __shfl_xor(p, 4, 64);
        p += __shfl_xor(p, 8, 64);
        int row = rowBase + 4 * q + r;
        if (n == 0 && row < N_NODES) sOut[row] = p;
    }
}

// ---------------------------------------------------------------------------
// CSR build
// ---------------------------------------------------------------------------
__global__ __launch_bounds__(256)
void hist_kernel(const int* __restrict__ e0a, int* __restrict__ counts)
{
    int i = blockIdx.x * 256 + threadIdx.x;
    if (i < N_EDGES / 4) {
        int4 e = ((const int4*)e0a)[i];
        atomicAdd(&counts[e.x], 1);
        atomicAdd(&counts[e.y], 1);
        atomicAdd(&counts[e.z], 1);
        atomicAdd(&counts[e.w], 1);
    }
}

__global__ __launch_bounds__(256)
void scan1_kernel(const int* __restrict__ counts, int* __restrict__ offsets,
                  int* __restrict__ blockSums)
{
    __shared__ int s[256];
    int t = threadIdx.x;
    int base = blockIdx.x * 1024 + t * 4;
    int c0 = (base + 0 < N_NODES) ? counts[base + 0] : 0;
    int c1 = (base + 1 < N_NODES) ? counts[base + 1] : 0;
    int c2 = (base + 2 < N_NODES) ? counts[base + 2] : 0;
    int c3 = (base + 3 < N_NODES) ? counts[base + 3] : 0;
    int tsum = c0 + c1 + c2 + c3;
    s[t] = tsum;
    __syncthreads();
    for (int off = 1; off < 256; off <<= 1) {
        int v = (t >= off) ? s[t - off] : 0;
        __syncthreads();
        s[t] += v;
        __syncthreads();
    }
    int excl = s[t] - tsum;
    if (base + 0 < N_NODES) offsets[base + 0] = excl;
    if (base + 1 < N_NODES) offsets[base + 1] = excl + c0;
    if (base + 2 < N_NODES) offsets[base + 2] = excl + c0 + c1;
    if (base + 3 < N_NODES) offsets[base + 3] = excl + c0 + c1 + c2;
    if (t == 255) blockSums[blockIdx.x] = s[255];
}

__global__ __launch_bounds__(128)
void scan2_kernel(int* __restrict__ blockSums)
{
    __shared__ int s[128];
    int t = threadIdx.x;
    int v = (t < SCAN_BLOCKS) ? blockSums[t] : 0;
    s[t] = v;
    __syncthreads();
    for (int off = 1; off < 128; off <<= 1) {
        int u = (t >= off) ? s[t - off] : 0;
        __syncthreads();
        s[t] += u;
        __syncthreads();
    }
    if (t < SCAN_BLOCKS) blockSums[t] = s[t] - v;   // exclusive
}

__global__ __launch_bounds__(256)
void scan3_kernel(int* __restrict__ offsets, int* __restrict__ cursor,
                  const int* __restrict__ blockSums)
{
    int t = threadIdx.x;
    int base = blockIdx.x * 1024 + t * 4;
    int add = blockSums[blockIdx.x];
    #pragma unroll
    for (int k = 0; k < 4; ++k) {
        int i = base + k;
        if (i < N_NODES) {
            int v = offsets[i] + add;
            offsets[i] = v;
            cursor[i] = v;
        }
    }
}

// scatter: edge score + packed record (e1, e2, ex, pad) at dest-sorted pos
__global__ __launch_bounds__(256)
void scatter_kernel(const int* __restrict__ e0a, const int* __restrict__ e1a,
                    const int* __restrict__ e2a,
                    const float* __restrict__ p0, const float* __restrict__ q1,
                    const float* __restrict__ q2, const float* __restrict__ b_att,
                    int* __restrict__ cursor, float4* __restrict__ rec)
{
    int i = blockIdx.x * 256 + threadIdx.x;
    if (i < N_EDGES) {
        int e0 = e0a[i], e1 = e1a[i], e2 = e2a[i];
        float x = p0[e0] + q1[e1] + q2[e2] + b_att[0];
        // tanh in [-1,1] => exp(tanh) safe; softmax shift-invariance makes
        // skipping the segment-max exact.
        float ex = __expf(tanhf(x));
        int pos = atomicAdd(&cursor[e0], 1);
        rec[pos] = make_float4(__int_as_float(e1), __int_as_float(e2), ex, 0.0f);
    }
}

// ---------------------------------------------------------------------------
// Aggregate (CSR, single fused pass): 16 lanes/node, zero atomics.
// out[n] = bias + H0[n]/3 + (1/(3*sum_ex)) * sum_e ex_e*(H1[e1]+H2[e2])
// ---------------------------------------------------------------------------
__global__ __launch_bounds__(256)
void aggregate_csr_kernel(const int* __restrict__ offsets, const int* __restrict__ counts,
                          const float4* __restrict__ rec,
                          const float* __restrict__ H0, const float* __restrict__ H1,
                          const float* __restrict__ H2,
                          const float* __restrict__ bias,
                          float* __restrict__ out)
{
    int gid  = blockIdx.x * 256 + threadIdx.x;
    int node = gid >> 4;
    int sub  = gid & 15;
    if (node >= N_NODES) return;

    int start = offsets[node];
    int cnt   = counts[node];

    float denom = 0.0f;
    float ax = 0.0f, ay = 0.0f, az = 0.0f, aw = 0.0f;
    for (int j = 0; j < cnt; ++j) {
        float4 r = rec[start + j];                 // broadcast across 16 lanes
        int e1 = __float_as_int(r.x);
        int e2 = __float_as_int(r.y);
        float w = r.z;
        float4 h1 = *(const float4*)&H1[(size_t)e1 * HID + 4 * sub];
        float4 h2 = *(const float4*)&H2[(size_t)e2 * HID + 4 * sub];
        denom += w;
        ax = fmaf(w, h1.x + h2.x, ax);
        ay = fmaf(w, h1.y + h2.y, ay);
        az = fmaf(w, h1.z + h2.z, az);
        aw = fmaf(w, h1.w + h2.w, aw);
    }

    float4 h0 = *(const float4*)&H0[(size_t)node * HID + 4 * sub];
    float4 bv = *(const float4*)&bias[4 * sub];
    float third = (cnt > 0) ? (1.0f / 3.0f) : 0.0f;
    float inv   = (cnt > 0) ? 1.0f / (3.0f * denom) : 0.0f;

    float4 o;
    o.x = bv.x + third * h0.x + inv * ax;
    o.y = bv.y + third * h0.y + inv * ay;
    o.z = bv.z + third * h0.z + inv * az;
    o.w = bv.w + third * h0.w + inv * aw;
    *(float4*)&out[(size_t)node * HID + 4 * sub] = o;
}

// ---------------------------------------------------------------------------
extern "C" void kernel_launch(void* const* d_in, const int* in_sizes, int n_in,
                              void* d_out, int out_size, void* d_ws, size_t ws_size,
                              hipStream_t stream)
{
    const float* feat0  = (const float*)d_in[0];
    const float* feat1  = (const float*)d_in[1];
    const float* feat2  = (const float*)d_in[2];
    const int*   edge0  = (const int*)d_in[3];
    const int*   edge1  = (const int*)d_in[4];
    const int*   edge2  = (const int*)d_in[5];
    const float* W_feat = (const float*)d_in[6];
    const float* b_feat = (const float*)d_in[7];
    const float* W_att  = (const float*)d_in[8];
    const float* b_att  = (const float*)d_in[9];
    const float* bias   = (const float*)d_in[10];
    float* out = (float*)d_out;

    // workspace layout (rec first for 16B alignment)
    float4* rec = (float4*)d_ws;                       // 1M float4 = 16 MB
    float* H0   = (float*)(rec + N_EDGES);             // 6.4M floats
    float* H1   = H0 + (size_t)N_NODES * HID;
    float* H2   = H1 + (size_t)N_NODES * HID;
    float* p0   = H2 + (size_t)N_NODES * HID;
    float* q1   = p0 + N_NODES;
    float* q2   = q1 + N_NODES;
    int* counts    = (int*)(q2 + N_NODES);
    int* offsets   = counts + N_NODES;
    int* cursor    = offsets + N_NODES;
    int* blockSums = cursor + N_NODES;                 // 128
    // total ~95.3 MB

    hipMemsetAsync(counts, 0, N_NODES * sizeof(int), stream);

    dim3 blk(256);
    dim3 gemmGrid((N_NODES + 63) / 64, 3);
    lin_att_mfma<<<gemmGrid, blk, 0, stream>>>(feat0, feat1, feat2,
                                               W_feat, b_feat, W_att,
                                               H0, H1, H2, p0, q1, q2);

    hist_kernel<<<(N_EDGES / 4 + 255) / 256, blk, 0, stream>>>(edge0, counts);
    scan1_kernel<<<SCAN_BLOCKS, blk, 0, stream>>>(counts, offsets, blockSums);
    scan2_kernel<<<1, 128, 0, stream>>>(blockSums);
    scan3_kernel<<<SCAN_BLOCKS, blk, 0, stream>>>(offsets, cursor, blockSums);

    scatter_kernel<<<(N_EDGES + 255) / 256, blk, 0, stream>>>(
        edge0, edge1, edge2, p0, q1, q2, b_att, cursor, rec);

    aggregate_csr_kernel<<<((size_t)N_NODES * 16 + 255) / 256, blk, 0, stream>>>(
        offsets, counts, rec, H0, H1, H2, bias, out);
}

// Round 6
// 360.202 us; speedup vs baseline: 3.5472x; 1.0951x over previous
//
#include <hip/hip_runtime.h>
#include <math.h>

#define IN_F 128
#define HID 64
#define N_NODES 100000
#define N_EDGES 1000000
#define SCAN_BLOCKS 98   // ceil(N_NODES / 1024)

typedef __attribute__((ext_vector_type(8))) short bf16x8;
typedef __attribute__((ext_vector_type(4))) float f32x4;
typedef __attribute__((ext_vector_type(4))) unsigned short u16x4;

// round-to-nearest-even fp32 -> bf16 (inputs finite)
static __device__ __forceinline__ short f2bf(float f) {
    union { float f; unsigned u; } v; v.f = f;
    unsigned r = v.u + 0x7fffu + ((v.u >> 16) & 1u);
    return (short)(r >> 16);
}
static __device__ __forceinline__ unsigned short f2bfu(float f) {
    union { float f; unsigned u; } v; v.f = f;
    unsigned r = v.u + 0x7fffu + ((v.u >> 16) & 1u);
    return (unsigned short)(r >> 16);
}
static __device__ __forceinline__ float bf2f(unsigned short u) {
    union { unsigned u; float f; } v; v.u = ((unsigned)u) << 16; return v.f;
}

// ---------------------------------------------------------------------------
// Pack W ([128][64] fp32) into bf16 B-fragment layout:
//   entry (c*4+s)*64 + l  holds 8 bf16 = W[k][16c+n], k=32s+8q+j, l=16q+n
// ---------------------------------------------------------------------------
__global__ __launch_bounds__(256)
void pack_w_kernel(const float* __restrict__ W, short* __restrict__ Wpk)
{
    int i = blockIdx.x * 256 + threadIdx.x;   // 1024 entries
    if (i < 1024) {
        int l = i & 63, cs = i >> 6;
        int c = cs >> 2, s = cs & 3;
        int n = l & 15, q = l >> 4;
        short v[8];
        #pragma unroll
        for (int j = 0; j < 8; ++j)
            v[j] = f2bf(W[(32 * s + 8 * q + j) * HID + 16 * c + n]);
        *(bf16x8*)&Wpk[(size_t)i * 8] = *(const bf16x8*)v;
    }
}

// ---------------------------------------------------------------------------
// Fused 3x GEMM via bf16 MFMA, zero LDS / zero syncthreads.
// blockIdx.y selects feat & outputs. 4 waves/block, 16 rows x 64 cols each.
//   A-frag: lane m=l&15, k=8*quad+j  (global fp32 -> inline bf16)
//   B-frag: from pre-packed Wpk (coalesced 16B loads, L2-hot)
//   C/D:    col=l&15, row=4*quad+reg  [m89/m91 verified]
// which==0 -> H0 fp32 + p0 ; which==1/2 -> H bf16 + q1/q2
// ---------------------------------------------------------------------------
__global__ __launch_bounds__(256)
void lin_att_mfma(const float* __restrict__ feat0, const float* __restrict__ feat1,
                  const float* __restrict__ feat2,
                  const short* __restrict__ Wpk, const float* __restrict__ b_feat,
                  const float* __restrict__ W_att,
                  float* __restrict__ H0,
                  unsigned short* __restrict__ H1b, unsigned short* __restrict__ H2b,
                  float* __restrict__ p0, float* __restrict__ q1, float* __restrict__ q2)
{
    const int which = blockIdx.y;
    const float* feat = (which == 0) ? feat0 : (which == 1) ? feat1 : feat2;
    float* sOut = (which == 0) ? p0 : (which == 1) ? q1 : q2;
    unsigned short* Hb = (which == 1) ? H1b : H2b;

    const int t  = threadIdx.x;
    const int wv = t >> 6;
    const int l  = t & 63;
    const int n  = l & 15;
    const int q  = l >> 4;
    const int rowBase = blockIdx.x * 64 + wv * 16;

    // B-fragments straight from packed global (16 x dwordx4, L2 broadcast)
    bf16x8 Bf[4][4];
    #pragma unroll
    for (int c = 0; c < 4; ++c)
        #pragma unroll
        for (int s = 0; s < 4; ++s)
            Bf[c][s] = *(const bf16x8*)&Wpk[((c * 4 + s) * 64 + l) * 8];

    f32x4 acc[4];
    #pragma unroll
    for (int c = 0; c < 4; ++c) {
        float bv = b_feat[16 * c + n];
        acc[c][0] = bv; acc[c][1] = bv; acc[c][2] = bv; acc[c][3] = bv;
    }

    const int gRow = rowBase + n;
    const int lr = (gRow < N_NODES) ? gRow : (N_NODES - 1);   // clamp loads

    #pragma unroll
    for (int s = 0; s < 4; ++s) {
        const float* ap = &feat[(size_t)lr * IN_F + 32 * s + 8 * q];
        float4 x0 = *(const float4*)ap;
        float4 x1 = *(const float4*)(ap + 4);
        bf16x8 a;
        a[0] = f2bf(x0.x); a[1] = f2bf(x0.y); a[2] = f2bf(x0.z); a[3] = f2bf(x0.w);
        a[4] = f2bf(x1.x); a[5] = f2bf(x1.y); a[6] = f2bf(x1.z); a[7] = f2bf(x1.w);
        #pragma unroll
        for (int c = 0; c < 4; ++c)
            acc[c] = __builtin_amdgcn_mfma_f32_16x16x32_bf16(a, Bf[c][s], acc[c], 0, 0, 0);
    }

    // epilogue: store H (+ fused attention scalar in fp32)
    float part[4] = {0.f, 0.f, 0.f, 0.f};
    #pragma unroll
    for (int c = 0; c < 4; ++c) {
        int col = 16 * c + n;
        float a0 = W_att[col], a1 = W_att[HID + col];
        float ae = (which == 0) ? (a0 + a1 * (1.0f / 3.0f)) : (a1 * (1.0f / 3.0f));
        #pragma unroll
        for (int r = 0; r < 4; ++r) {
            int row = rowBase + 4 * q + r;
            if (row < N_NODES) {
                if (which == 0) H0[(size_t)row * HID + col] = acc[c][r];
                else            Hb[(size_t)row * HID + col] = f2bfu(acc[c][r]);
            }
            part[r] = fmaf(acc[c][r], ae, part[r]);
        }
    }
    #pragma unroll
    for (int r = 0; r < 4; ++r) {
        float p = part[r];
        p += __shfl_xor(p, 1, 64);
        p += __shfl_xor(p, 2, 64);
        p += __shfl_xor(p, 4, 64);
        p += __shfl_xor(p, 8, 64);
        int row = rowBase + 4 * q + r;
        if (n == 0 && row < N_NODES) sOut[row] = p;
    }
}

// ---------------------------------------------------------------------------
// CSR build
// ---------------------------------------------------------------------------
__global__ __launch_bounds__(256)
void hist_kernel(const int* __restrict__ e0a, int* __restrict__ counts)
{
    int i = blockIdx.x * 256 + threadIdx.x;
    if (i < N_EDGES / 4) {
        int4 e = ((const int4*)e0a)[i];
        atomicAdd(&counts[e.x], 1);
        atomicAdd(&counts[e.y], 1);
        atomicAdd(&counts[e.z], 1);
        atomicAdd(&counts[e.w], 1);
    }
}

__global__ __launch_bounds__(256)
void scan1_kernel(const int* __restrict__ counts, int* __restrict__ offsets,
                  int* __restrict__ blockSums)
{
    __shared__ int s[256];
    int t = threadIdx.x;
    int base = blockIdx.x * 1024 + t * 4;
    int c0 = (base + 0 < N_NODES) ? counts[base + 0] : 0;
    int c1 = (base + 1 < N_NODES) ? counts[base + 1] : 0;
    int c2 = (base + 2 < N_NODES) ? counts[base + 2] : 0;
    int c3 = (base + 3 < N_NODES) ? counts[base + 3] : 0;
    int tsum = c0 + c1 + c2 + c3;
    s[t] = tsum;
    __syncthreads();
    for (int off = 1; off < 256; off <<= 1) {
        int v = (t >= off) ? s[t - off] : 0;
        __syncthreads();
        s[t] += v;
        __syncthreads();
    }
    int excl = s[t] - tsum;
    if (base + 0 < N_NODES) offsets[base + 0] = excl;
    if (base + 1 < N_NODES) offsets[base + 1] = excl + c0;
    if (base + 2 < N_NODES) offsets[base + 2] = excl + c0 + c1;
    if (base + 3 < N_NODES) offsets[base + 3] = excl + c0 + c1 + c2;
    if (t == 255) blockSums[blockIdx.x] = s[255];
}

__global__ __launch_bounds__(128)
void scan2_kernel(int* __restrict__ blockSums)
{
    __shared__ int s[128];
    int t = threadIdx.x;
    int v = (t < SCAN_BLOCKS) ? blockSums[t] : 0;
    s[t] = v;
    __syncthreads();
    for (int off = 1; off < 128; off <<= 1) {
        int u = (t >= off) ? s[t - off] : 0;
        __syncthreads();
        s[t] += u;
        __syncthreads();
    }
    if (t < SCAN_BLOCKS) blockSums[t] = s[t] - v;   // exclusive
}

__global__ __launch_bounds__(256)
void scan3_kernel(int* __restrict__ offsets, int* __restrict__ cursor,
                  const int* __restrict__ blockSums)
{
    int t = threadIdx.x;
    int base = blockIdx.x * 1024 + t * 4;
    int add = blockSums[blockIdx.x];
    #pragma unroll
    for (int k = 0; k < 4; ++k) {
        int i = base + k;
        if (i < N_NODES) {
            int v = offsets[i] + add;
            offsets[i] = v;
            cursor[i] = v;
        }
    }
}

// scatter: edge score + packed record (e1, e2, ex, pad) at dest-sorted pos
__global__ __launch_bounds__(256)
void scatter_kernel(const int* __restrict__ e0a, const int* __restrict__ e1a,
                    const int* __restrict__ e2a,
                    const float* __restrict__ p0, const float* __restrict__ q1,
                    const float* __restrict__ q2, const float* __restrict__ b_att,
                    int* __restrict__ cursor, float4* __restrict__ rec)
{
    int i = blockIdx.x * 256 + threadIdx.x;
    if (i < N_EDGES) {
        int e0 = e0a[i], e1 = e1a[i], e2 = e2a[i];
        float x = p0[e0] + q1[e1] + q2[e2] + b_att[0];
        // tanh in [-1,1] => exp(tanh) safe; softmax shift-invariance makes
        // skipping the segment-max exact.
        float ex = __expf(tanhf(x));
        int pos = atomicAdd(&cursor[e0], 1);
        rec[pos] = make_float4(__int_as_float(e1), __int_as_float(e2), ex, 0.0f);
    }
}

// ---------------------------------------------------------------------------
// Aggregate (CSR, fused): 16 lanes/node, zero atomics, bf16 gathers.
// out[n] = bias + H0[n]/3 + (1/(3*sum_ex)) * sum_e ex_e*(H1[e1]+H2[e2])
// ---------------------------------------------------------------------------
__global__ __launch_bounds__(256)
void aggregate_csr_kernel(const int* __restrict__ offsets, const int* __restrict__ counts,
                          const float4* __restrict__ rec,
                          const float* __restrict__ H0,
                          const unsigned short* __restrict__ H1b,
                          const unsigned short* __restrict__ H2b,
                          const float* __restrict__ bias,
                          float* __restrict__ out)
{
    int gid  = blockIdx.x * 256 + threadIdx.x;
    int node = gid >> 4;
    int sub  = gid & 15;
    if (node >= N_NODES) return;

    int start = offsets[node];
    int cnt   = counts[node];

    float denom = 0.0f;
    float ax = 0.0f, ay = 0.0f, az = 0.0f, aw = 0.0f;
    for (int j = 0; j < cnt; ++j) {
        float4 r = rec[start + j];                 // broadcast across 16 lanes
        int e1 = __float_as_int(r.x);
        int e2 = __float_as_int(r.y);
        float w = r.z;
        u16x4 h1 = *(const u16x4*)&H1b[(size_t)e1 * HID + 4 * sub];
        u16x4 h2 = *(const u16x4*)&H2b[(size_t)e2 * HID + 4 * sub];
        denom += w;
        ax = fmaf(w, bf2f(h1.x) + bf2f(h2.x), ax);
        ay = fmaf(w, bf2f(h1.y) + bf2f(h2.y), ay);
        az = fmaf(w, bf2f(h1.z) + bf2f(h2.z), az);
        aw = fmaf(w, bf2f(h1.w) + bf2f(h2.w), aw);
    }

    float4 h0 = *(const float4*)&H0[(size_t)node * HID + 4 * sub];
    float4 bv = *(const float4*)&bias[4 * sub];
    float third = (cnt > 0) ? (1.0f / 3.0f) : 0.0f;
    float inv   = (cnt > 0) ? 1.0f / (3.0f * denom) : 0.0f;

    float4 o;
    o.x = bv.x + third * h0.x + inv * ax;
    o.y = bv.y + third * h0.y + inv * ay;
    o.z = bv.z + third * h0.z + inv * az;
    o.w = bv.w + third * h0.w + inv * aw;
    *(float4*)&out[(size_t)node * HID + 4 * sub] = o;
}

// ---------------------------------------------------------------------------
extern "C" void kernel_launch(void* const* d_in, const int* in_sizes, int n_in,
                              void* d_out, int out_size, void* d_ws, size_t ws_size,
                              hipStream_t stream)
{
    const float* feat0  = (const float*)d_in[0];
    const float* feat1  = (const float*)d_in[1];
    const float* feat2  = (const float*)d_in[2];
    const int*   edge0  = (const int*)d_in[3];
    const int*   edge1  = (const int*)d_in[4];
    const int*   edge2  = (const int*)d_in[5];
    const float* W_feat = (const float*)d_in[6];
    const float* b_feat = (const float*)d_in[7];
    const float* W_att  = (const float*)d_in[8];
    const float* b_att  = (const float*)d_in[9];
    const float* bias   = (const float*)d_in[10];
    float* out = (float*)d_out;

    // workspace layout (16B-aligned chunks first)
    float4* rec  = (float4*)d_ws;                          // 1M float4 = 16 MB
    short*  Wpk  = (short*)(rec + N_EDGES);                // 8192 shorts (16 KB)
    float*  H0   = (float*)(Wpk + 8192);                   // 6.4M floats
    unsigned short* H1b = (unsigned short*)(H0 + (size_t)N_NODES * HID); // 6.4M
    unsigned short* H2b = H1b + (size_t)N_NODES * HID;                   // 6.4M
    float*  p0   = (float*)(H2b + (size_t)N_NODES * HID);
    float*  q1   = p0 + N_NODES;
    float*  q2   = q1 + N_NODES;
    int* counts    = (int*)(q2 + N_NODES);
    int* offsets   = counts + N_NODES;
    int* cursor    = offsets + N_NODES;
    int* blockSums = cursor + N_NODES;                     // 128
    // total ~72 MB

    (void)hipMemsetAsync(counts, 0, N_NODES * sizeof(int), stream);

    dim3 blk(256);
    pack_w_kernel<<<4, blk, 0, stream>>>(W_feat, Wpk);

    dim3 gemmGrid((N_NODES + 63) / 64, 3);
    lin_att_mfma<<<gemmGrid, blk, 0, stream>>>(feat0, feat1, feat2,
                                               Wpk, b_feat, W_att,
                                               H0, H1b, H2b, p0, q1, q2);

    hist_kernel<<<(N_EDGES / 4 + 255) / 256, blk, 0, stream>>>(edge0, counts);
    scan1_kernel<<<SCAN_BLOCKS, blk, 0, stream>>>(counts, offsets, blockSums);
    scan2_kernel<<<1, 128, 0, stream>>>(blockSums);
    scan3_kernel<<<SCAN_BLOCKS, blk, 0, stream>>>(offsets, cursor, blockSums);

    scatter_kernel<<<(N_EDGES + 255) / 256, blk, 0, stream>>>(
        edge0, edge1, edge2, p0, q1, q2, b_att, cursor, rec);

    aggregate_csr_kernel<<<((size_t)N_NODES * 16 + 255) / 256, blk, 0, stream>>>(
        offsets, counts, rec, H0, H1b, H2b, bias, out);
}